// Round 1
// baseline (241.285 us; speedup 1.0000x reference)
//
#include <hip/hip_runtime.h>
#include <math.h>

#define BATCH 8
#define FDIM  64
#define NDIM  2048
#define MTOT  (BATCH * FDIM * NDIM)   // 1048576 total elements for std
#define TN    64
#define TM    64

// ws layout (floats):
//   [0 .. BATCH*NDIM)      colsq[b*NDIM + n] = sum_f emb[b,f,n]^2  (raw, unscaled)
//   [BATCH*NDIM]           global sum  accumulator
//   [BATCH*NDIM + 1]       global sumsq accumulator

__global__ __launch_bounds__(256) void colsq_reduce_kernel(
        const float* __restrict__ emb, float* __restrict__ ws) {
    int idx = blockIdx.x * blockDim.x + threadIdx.x;   // 0 .. BATCH*NDIM-1
    int b = idx >> 11;          // / NDIM
    int n = idx & (NDIM - 1);
    const float* p = emb + (size_t)b * FDIM * NDIM + n;
    float s = 0.f, q = 0.f;
#pragma unroll
    for (int f = 0; f < FDIM; ++f) {
        float v = p[(size_t)f * NDIM];
        s += v;
        q += v * v;
    }
    ws[idx] = q;

    // wave64 reduction of s, q
#pragma unroll
    for (int off = 32; off > 0; off >>= 1) {
        s += __shfl_down(s, off, 64);
        q += __shfl_down(q, off, 64);
    }
    __shared__ float ls[4], lq[4];
    int lane = threadIdx.x & 63;
    int wv = threadIdx.x >> 6;
    if (lane == 0) { ls[wv] = s; lq[wv] = q; }
    __syncthreads();
    if (threadIdx.x == 0) {
        float S = 0.f, Q = 0.f;
#pragma unroll
        for (int w = 0; w < 4; ++w) { S += ls[w]; Q += lq[w]; }
        atomicAdd(&ws[BATCH * NDIM], S);
        atomicAdd(&ws[BATCH * NDIM + 1], Q);
    }
}

__global__ __launch_bounds__(256) void gauss_kernel(
        const float* __restrict__ emb, const float* __restrict__ ws,
        float* __restrict__ out) {
    __shared__ float As[FDIM][TN];   // [k][n]
    __shared__ float Bs[FDIM][TM];   // [k][m]

    const int b  = blockIdx.z;
    const int n0 = blockIdx.y * TN;
    const int m0 = blockIdx.x * TM;
    const float* eb = emb + (size_t)b * FDIM * NDIM;
    const int tid = threadIdx.x;

    // Stage both 64x64 fp32 tiles: 256 threads x 4 rows x float4
    {
        const int c4 = (tid & 15) * 4;
        const int f0 = tid >> 4;       // 0..15
#pragma unroll
        for (int r = 0; r < 4; ++r) {
            int f = f0 + r * 16;
            *(float4*)&As[f][c4] = *(const float4*)&eb[(size_t)f * NDIM + n0 + c4];
            *(float4*)&Bs[f][c4] = *(const float4*)&eb[(size_t)f * NDIM + m0 + c4];
        }
    }
    __syncthreads();

    const int tx = tid & 15;    // m group
    const int ty = tid >> 4;    // n group

    float acc[4][4] = {};
#pragma unroll
    for (int k = 0; k < FDIM; ++k) {
        float4 a4 = *(float4*)&As[k][ty * 4];
        float4 b4 = *(float4*)&Bs[k][tx * 4];
        float av[4] = {a4.x, a4.y, a4.z, a4.w};
        float bv[4] = {b4.x, b4.y, b4.z, b4.w};
#pragma unroll
        for (int i = 0; i < 4; ++i)
#pragma unroll
            for (int j = 0; j < 4; ++j)
                acc[i][j] += av[i] * bv[j];
    }

    // std (ddof=1) over all elements, folded scale
    const float sum   = ws[BATCH * NDIM];
    const float sumsq = ws[BATCH * NDIM + 1];
    const float M = (float)MTOT;
    const float var = (sumsq - sum * sum / M) / (M - 1.0f);
    const float invscale = 1.0f / (var * (float)FDIM * 2.0f);   // SIGMA = 2

    const float* colsq = ws;
    float qn[4], qm[4];
#pragma unroll
    for (int i = 0; i < 4; ++i) qn[i] = colsq[b * NDIM + n0 + ty * 4 + i];
#pragma unroll
    for (int j = 0; j < 4; ++j) qm[j] = colsq[b * NDIM + m0 + tx * 4 + j];

    const size_t obase = (size_t)b * NDIM * NDIM;
#pragma unroll
    for (int i = 0; i < 4; ++i) {
        int n = n0 + ty * 4 + i;
        float r[4];
#pragma unroll
        for (int j = 0; j < 4; ++j) {
            float d = qn[i] + qm[j] - 2.0f * acc[i][j];
            r[j] = __expf(-d * invscale);
        }
        float4 o = make_float4(r[0], r[1], r[2], r[3]);
        *(float4*)&out[obase + (size_t)n * NDIM + m0 + tx * 4] = o;
    }
}

extern "C" void kernel_launch(void* const* d_in, const int* in_sizes, int n_in,
                              void* d_out, int out_size, void* d_ws, size_t ws_size,
                              hipStream_t stream) {
    // d_in[0] = adj_in [8,2048,2048] fp32 — UNUSED by the reference.
    // d_in[1] = emb_in [8,64,2048] fp32.
    const float* emb = (const float*)d_in[1];
    float* out = (float*)d_out;
    float* ws  = (float*)d_ws;

    // Zero the two scalar accumulators (ws is re-poisoned 0xAA before each call).
    hipMemsetAsync(ws + BATCH * NDIM, 0, 2 * sizeof(float), stream);

    colsq_reduce_kernel<<<(BATCH * NDIM) / 256, 256, 0, stream>>>(emb, ws);

    dim3 grid(NDIM / TM, NDIM / TN, BATCH);
    gauss_kernel<<<grid, 256, 0, stream>>>(emb, ws, out);
}

// Round 2
// 215.645 us; speedup vs baseline: 1.1189x; 1.1189x over previous
//
#include <hip/hip_runtime.h>
#include <math.h>

#define BATCH 8
#define FDIM  64
#define NDIM  2048
#define MTOT  (BATCH * FDIM * NDIM)
#define SIGMA 2.0f

#define COLSQ_N (BATCH * NDIM)          // 16384 floats of colsq
#define EMBT_OFF_FLOATS 16400           // embT (bf16) starts at byte 65600 (64B aligned)
// ws usage: 65600 B + 8*2048*64*2 B = ~2.07 MiB  (<< out_size 128 MiB)

typedef __attribute__((ext_vector_type(8))) short bf16x8;
typedef __attribute__((ext_vector_type(4))) float f32x4;

static __device__ inline unsigned short f2bf(float x) {
    unsigned int u = __float_as_uint(x);
    unsigned int r = (u + 0x7fffu + ((u >> 16) & 1u)) >> 16;   // RTNE
    return (unsigned short)r;
}

// Kernel A: per-column sumsq (colsq), global sum/sumsq, and fp32->bf16
// transposed copy embT[b][n][f] so the GEMM reads 16B-contiguous rows.
__global__ __launch_bounds__(256) void prep_kernel(
        const float* __restrict__ emb, float* __restrict__ ws) {
    const int b = blockIdx.x >> 3;
    const int n = ((blockIdx.x & 7) << 8) + threadIdx.x;
    const float* p = emb + (size_t)b * FDIM * NDIM + n;
    unsigned short* embT = (unsigned short*)(ws + EMBT_OFF_FLOATS);
    unsigned short* dst = embT + ((size_t)(b * NDIM + n)) * FDIM;

    float s = 0.f, q = 0.f;
#pragma unroll
    for (int f0 = 0; f0 < FDIM; f0 += 8) {
        unsigned int wv[4];
#pragma unroll
        for (int j = 0; j < 4; ++j) {
            float a = p[(size_t)(f0 + 2 * j) * NDIM];
            float c = p[(size_t)(f0 + 2 * j + 1) * NDIM];
            s += a + c;
            q += a * a + c * c;
            wv[j] = (unsigned)f2bf(a) | ((unsigned)f2bf(c) << 16);
        }
        *(uint4*)(dst + f0) = make_uint4(wv[0], wv[1], wv[2], wv[3]);
    }
    ws[b * NDIM + n] = q;

    // block reduction of s, q -> global atomics
#pragma unroll
    for (int off = 32; off > 0; off >>= 1) {
        s += __shfl_down(s, off, 64);
        q += __shfl_down(q, off, 64);
    }
    __shared__ float ls[4], lq[4];
    int lane = threadIdx.x & 63, wv_ = threadIdx.x >> 6;
    if (lane == 0) { ls[wv_] = s; lq[wv_] = q; }
    __syncthreads();
    if (threadIdx.x == 0) {
        float S = 0.f, Q = 0.f;
#pragma unroll
        for (int w = 0; w < 4; ++w) { S += ls[w]; Q += lq[w]; }
        atomicAdd(&ws[COLSQ_N], S);
        atomicAdd(&ws[COLSQ_N + 1], Q);
    }
}

// Kernel B: 128x128 output tile per block. bf16 MFMA 16x16x32, K=64.
// LDS tiles stored [row][k] with chunk-XOR swizzle (16B chunks, c ^ (row&7)).
__global__ __launch_bounds__(256) void gauss_mfma_kernel(
        const float* __restrict__ ws, float* __restrict__ out) {
    __shared__ unsigned short At[128 * 64];
    __shared__ unsigned short Bt[128 * 64];
    __shared__ float qs[256];   // [0..127]: -colsq[n0+i]*sc, [128..255]: -colsq[m0+j]*sc

    const int b = blockIdx.z;
    const int n0 = blockIdx.y * 128, m0 = blockIdx.x * 128;
    const int t = threadIdx.x;
    const unsigned short* embT = (const unsigned short*)(ws + EMBT_OFF_FLOATS);
    const unsigned short* baseA = embT + ((size_t)(b * NDIM + n0)) * FDIM;
    const unsigned short* baseB = embT + ((size_t)(b * NDIM + m0)) * FDIM;

    // fold std + /F + /SIGMA into one scale
    const float sum = ws[COLSQ_N], sumsq = ws[COLSQ_N + 1];
    const float M = (float)MTOT;
    const float var = (sumsq - sum * sum / M) / (M - 1.0f);
    const float sc = 1.0f / (var * (float)FDIM * SIGMA);

    {   // stage both tiles: 16B per thread per iter, swizzled LDS store
        const int row = t >> 3, c = t & 7;
#pragma unroll
        for (int it = 0; it < 4; ++it) {
            int r = row + it * 32;
            int slot = c ^ (r & 7);
            *(float4*)&At[r * 64 + slot * 8] = *(const float4*)(baseA + r * 64 + c * 8);
            *(float4*)&Bt[r * 64 + slot * 8] = *(const float4*)(baseB + r * 64 + c * 8);
        }
        if (t < 128) qs[t] = -ws[b * NDIM + n0 + t] * sc;
        else         qs[t] = -ws[b * NDIM + m0 + (t - 128)] * sc;
    }
    __syncthreads();

    const int lane = t & 63;
    const int w = t >> 6;
    const int wn = (w & 1) * 64, wm = (w >> 1) * 64;   // wave's 64x64 quadrant
    const int mrow = lane & 15;
    const int quad = lane >> 4;

    f32x4 acc[4][4] = {};
#pragma unroll
    for (int ks = 0; ks < 2; ++ks) {
        bf16x8 af[4], bf_[4];
#pragma unroll
        for (int i = 0; i < 4; ++i) {
            int ra = wn + i * 16 + mrow;
            int ca = (ks * 4 + quad) ^ (ra & 7);
            af[i] = *(bf16x8*)&At[ra * 64 + ca * 8];
            int rb = wm + i * 16 + mrow;
            int cb = (ks * 4 + quad) ^ (rb & 7);
            bf_[i] = *(bf16x8*)&Bt[rb * 64 + cb * 8];
        }
#pragma unroll
        for (int i = 0; i < 4; ++i)
#pragma unroll
            for (int j = 0; j < 4; ++j)
                acc[i][j] = __builtin_amdgcn_mfma_f32_16x16x32_bf16(
                        af[i], bf_[j], acc[i][j], 0, 0, 0);
    }

    // epilogue: out = exp(-(cn+cm)*sc + 2*sc*gram)
    const float s2 = 2.0f * sc;
    const size_t obase = (size_t)b * NDIM * NDIM;
#pragma unroll
    for (int i = 0; i < 4; ++i) {
#pragma unroll
        for (int j = 0; j < 4; ++j) {
            int mcol = wm + j * 16 + mrow;
            float qm = qs[128 + mcol];
#pragma unroll
            for (int r = 0; r < 4; ++r) {
                int nrow = wn + i * 16 + quad * 4 + r;
                float arg = fmaf(s2, acc[i][j][r], qs[nrow] + qm);
                out[obase + (size_t)(n0 + nrow) * NDIM + (m0 + mcol)] = __expf(arg);
            }
        }
    }
}

extern "C" void kernel_launch(void* const* d_in, const int* in_sizes, int n_in,
                              void* d_out, int out_size, void* d_ws, size_t ws_size,
                              hipStream_t stream) {
    // d_in[0] = adj_in (unused). d_in[1] = emb_in [8,64,2048] fp32.
    const float* emb = (const float*)d_in[1];
    float* out = (float*)d_out;
    float* ws  = (float*)d_ws;

    hipMemsetAsync(ws + COLSQ_N, 0, 2 * sizeof(float), stream);
    prep_kernel<<<64, 256, 0, stream>>>(emb, ws);

    dim3 grid(NDIM / 128, NDIM / 128, BATCH);
    gauss_mfma_kernel<<<grid, 256, 0, stream>>>(ws, out);
}

// Round 3
// 210.924 us; speedup vs baseline: 1.1439x; 1.0224x over previous
//
#include <hip/hip_runtime.h>
#include <math.h>

#define BATCH 8
#define FDIM  64
#define NDIM  2048
#define MTOT  (BATCH * FDIM * NDIM)
#define SIGMA 2.0f

#define COLSQ_N (BATCH * NDIM)             // 16384 colsq floats
#define NPREP   256                        // prep block count
#define PSUM_OFF (COLSQ_N)                 // 256 per-block sums
#define PSQ_OFF  (COLSQ_N + NPREP)         // 256 per-block sumsqs
#define EMBT_OFF (COLSQ_N + 2 * NPREP)     // bf16 embT starts (byte 67584, 64B aligned)

typedef __attribute__((ext_vector_type(8))) short bf16x8;
typedef __attribute__((ext_vector_type(4))) float f32x4;

static __device__ inline unsigned short f2bf(float x) {
    unsigned int u = __float_as_uint(x);
    return (unsigned short)((u + 0x7fffu + ((u >> 16) & 1u)) >> 16);   // RTNE
}

// prep: 256 blocks x 1 wave, one column per thread. Produces:
//   colsq[b*NDIM+n], per-block partial (sum,sumsq) — no atomics, no memset —
//   and bf16 embT[b][n][f] for 16B-coalesced GEMM staging.
__global__ __launch_bounds__(64) void prep_kernel(
        const float* __restrict__ emb, float* __restrict__ ws) {
    const int blk = blockIdx.x;
    const int b = blk >> 5;
    const int n = ((blk & 31) << 6) + threadIdx.x;
    const float* p = emb + (size_t)b * FDIM * NDIM + n;
    unsigned short* dst = (unsigned short*)(ws + EMBT_OFF) + (size_t)(b * NDIM + n) * FDIM;

    float s = 0.f, q = 0.f;
#pragma unroll
    for (int f0 = 0; f0 < FDIM; f0 += 8) {
        unsigned int wv[4];
#pragma unroll
        for (int j = 0; j < 4; ++j) {
            float a = p[(size_t)(f0 + 2 * j) * NDIM];
            float c = p[(size_t)(f0 + 2 * j + 1) * NDIM];
            s += a + c;
            q += a * a + c * c;
            wv[j] = (unsigned)f2bf(a) | ((unsigned)f2bf(c) << 16);
        }
        *(uint4*)(dst + f0) = make_uint4(wv[0], wv[1], wv[2], wv[3]);
    }
    ws[b * NDIM + n] = q;

#pragma unroll
    for (int off = 32; off > 0; off >>= 1) {
        s += __shfl_down(s, off, 64);
        q += __shfl_down(q, off, 64);
    }
    if (threadIdx.x == 0) {
        ws[PSUM_OFF + blk] = s;
        ws[PSQ_OFF + blk] = q;
    }
}

// gauss: 128x128 tile/block, bf16 MFMA 16x16x32 with SWAPPED operands so the
// C/D regs span m (columns) -> dwordx4 coalesced stores. Reduces the 256
// prep partials in-block (one barrier covers staging + reduction).
__global__ __launch_bounds__(256) void gauss_mfma_kernel(
        const float* __restrict__ ws, float* __restrict__ out) {
    __shared__ unsigned short At[128 * 64];
    __shared__ unsigned short Bt[128 * 64];
    __shared__ float qs[256];     // raw colsq for the n-range (0..127) and m-range (128..255)
    __shared__ float red[8];      // 4 wave sums, 4 wave sumsqs

    const int b = blockIdx.z;
    const int n0 = blockIdx.y * 128, m0 = blockIdx.x * 128;
    const int t = threadIdx.x;
    const unsigned short* embT = (const unsigned short*)(ws + EMBT_OFF);
    const unsigned short* baseA = embT + (size_t)(b * NDIM + n0) * FDIM;
    const unsigned short* baseB = embT + (size_t)(b * NDIM + m0) * FDIM;

    // in-block reduction of prep partials (replaces memset+atomics)
    {
        float s = ws[PSUM_OFF + t];
        float q = ws[PSQ_OFF + t];
#pragma unroll
        for (int off = 32; off > 0; off >>= 1) {
            s += __shfl_down(s, off, 64);
            q += __shfl_down(q, off, 64);
        }
        if ((t & 63) == 0) { red[t >> 6] = s; red[4 + (t >> 6)] = q; }
    }

    // stage both tiles, XOR-swizzled LDS chunks (conflict-free b128 reads)
    {
        const int row = t >> 3, c = t & 7;
#pragma unroll
        for (int it = 0; it < 4; ++it) {
            int r = row + it * 32;
            int slot = c ^ (r & 7);
            *(float4*)&At[r * 64 + slot * 8] = *(const float4*)(baseA + r * 64 + c * 8);
            *(float4*)&Bt[r * 64 + slot * 8] = *(const float4*)(baseB + r * 64 + c * 8);
        }
        qs[t] = (t < 128) ? ws[b * NDIM + n0 + t] : ws[b * NDIM + m0 + (t - 128)];
    }
    __syncthreads();

    const int lane = t & 63;
    const int w = t >> 6;
    const int wn = (w & 1) * 64, wm = (w >> 1) * 64;
    const int mrow = lane & 15;
    const int quad = lane >> 4;

    f32x4 acc[4][4] = {};
#pragma unroll
    for (int ks = 0; ks < 2; ++ks) {
        bf16x8 af[4], bf_[4];
#pragma unroll
        for (int i = 0; i < 4; ++i) {
            int ra = wn + i * 16 + mrow;
            int ca = (ks * 4 + quad) ^ (ra & 7);
            af[i] = *(bf16x8*)&At[ra * 64 + ca * 8];
            int rb = wm + i * 16 + mrow;
            int cb = (ks * 4 + quad) ^ (rb & 7);
            bf_[i] = *(bf16x8*)&Bt[rb * 64 + cb * 8];
        }
#pragma unroll
        for (int i = 0; i < 4; ++i)
#pragma unroll
            for (int j = 0; j < 4; ++j)
                // swapped: D rows <- bf_ (m side), D cols <- af (n side)
                acc[i][j] = __builtin_amdgcn_mfma_f32_16x16x32_bf16(
                        bf_[j], af[i], acc[i][j], 0, 0, 0);
    }

    // finish the global reduction redundantly per thread (LDS broadcast reads)
    const float S = red[0] + red[1] + red[2] + red[3];
    const float Q = red[4] + red[5] + red[6] + red[7];
    const float M = (float)MTOT;
    const float var = (Q - S * S / M) / (M - 1.0f);
    const float sc = 1.0f / (var * (float)FDIM * SIGMA);
    const float s2 = 2.0f * sc;

    const size_t obase = (size_t)b * NDIM * NDIM;
#pragma unroll
    for (int i = 0; i < 4; ++i) {
        const int n = wn + i * 16 + mrow;                 // n index (lane&15 side)
        const float qnt = -sc * qs[n];
#pragma unroll
        for (int j = 0; j < 4; ++j) {
            const int mbase = wm + j * 16 + quad * 4;     // m index (reg side)
            f32x4 qm4 = *(f32x4*)&qs[128 + mbase];
            float4 o;
            o.x = __expf(fmaf(s2, acc[i][j][0], fmaf(-sc, qm4[0], qnt)));
            o.y = __expf(fmaf(s2, acc[i][j][1], fmaf(-sc, qm4[1], qnt)));
            o.z = __expf(fmaf(s2, acc[i][j][2], fmaf(-sc, qm4[2], qnt)));
            o.w = __expf(fmaf(s2, acc[i][j][3], fmaf(-sc, qm4[3], qnt)));
            *(float4*)&out[obase + (size_t)(n0 + n) * NDIM + (m0 + mbase)] = o;
        }
    }
}

extern "C" void kernel_launch(void* const* d_in, const int* in_sizes, int n_in,
                              void* d_out, int out_size, void* d_ws, size_t ws_size,
                              hipStream_t stream) {
    // d_in[0] = adj_in (unused by reference). d_in[1] = emb_in [8,64,2048] fp32.
    const float* emb = (const float*)d_in[1];
    float* out = (float*)d_out;
    float* ws  = (float*)d_ws;

    prep_kernel<<<NPREP, 64, 0, stream>>>(emb, ws);

    dim3 grid(NDIM / 128, NDIM / 128, BATCH);
    gauss_mfma_kernel<<<grid, 256, 0, stream>>>(ws, out);
}